// Round 2
// baseline (6519.027 us; speedup 1.0000x reference)
//
#include <hip/hip_runtime.h>
#include <hip/hip_bf16.h>

typedef __attribute__((ext_vector_type(8))) short short8;
typedef __attribute__((ext_vector_type(4))) float f32x4;
typedef unsigned short u16;
typedef unsigned int u32;

#define L_ 12
#define D_ 768
#define F_ 3072
#define M_ 16384   // B*S
#define P_ 768

__device__ __forceinline__ u16 f2bf(float f) {
  __hip_bfloat16 h = __float2bfloat16(f);
  return __builtin_bit_cast(u16, h);
}

__device__ __forceinline__ f32x4 mfma_bf16(short8 a, short8 b, f32x4 c) {
  return __builtin_amdgcn_mfma_f32_16x16x32_bf16(a, b, c, 0, 0, 0);
}

__device__ __forceinline__ float gelu_tanh(float x) {
  float u = 0.7978845608028654f * (x + 0.044715f * x * x * x);
  float e = __expf(2.0f * u);
  float t = 1.0f - 2.0f / (e + 1.0f);   // tanh(u), safe at +-inf
  return 0.5f * x * (1.0f + t);
}

// global -> LDS direct load, 16 bytes per lane. LDS dest must be wave-uniform
// base (HW adds lane*16). Global side: generic->AS1 cast (flat==global addr).
// LDS side: generic->AS3 addrspacecast (NOT an integer truncation).
__device__ __forceinline__ void glds16(const void* g, void* l) {
  __builtin_amdgcn_global_load_lds(
      (const __attribute__((address_space(1))) u32*)g,
      (__attribute__((address_space(3))) u32*)l, 16, 0, 0);
}

// ---------------------------------------------------------------- transpose+cvt
// src fp32 [z][R][C] -> dst bf16 [z][C][R]
__global__ __launch_bounds__(256) void wtrans_kernel(
    const float* __restrict__ src, u16* __restrict__ dst, int R, int C)
{
  __shared__ float tile[32][33];
  const size_t off = (size_t)blockIdx.z * R * C;
  const float* s = src + off;
  u16* d = dst + off;
  const int c0 = blockIdx.x * 32, r0 = blockIdx.y * 32;
  const int tx = threadIdx.x, ty = threadIdx.y;   // (32,8)
#pragma unroll
  for (int i = 0; i < 32; i += 8)
    tile[ty + i][tx] = s[(size_t)(r0 + ty + i) * C + c0 + tx];
  __syncthreads();
#pragma unroll
  for (int i = 0; i < 32; i += 8)
    d[(size_t)(c0 + ty + i) * R + r0 + tx] = f2bf(tile[tx][ty + i]);
}

// ---------------------------------------------------------------- embedding
__global__ __launch_bounds__(256) void embed_kernel(
    const int* __restrict__ ids, const float* __restrict__ tok,
    const float* __restrict__ pos, float* __restrict__ h)
{
  const int idx = blockIdx.x * 256 + threadIdx.x;  // 16384*192 float4 slots
  const int t = idx / 192;
  const int c = (idx - t * 192) * 4;
  const int s = t & 63;
  const int id = ids[t];
  const float4 te = *(const float4*)(tok + (size_t)id * 768 + c);
  const float4 pe = *(const float4*)(pos + (size_t)s * 768 + c);
  float4 r; r.x = te.x + pe.x; r.y = te.y + pe.y; r.z = te.z + pe.z; r.w = te.w + pe.w;
  *(float4*)&h[(size_t)t * 768 + c] = r;
}

// ---------------------------------------------------------------- layernorm
// one wave per row (4 rows / block). fp32 in, bf16 out (+ optional fp32 out)
template<bool FOUT>
__global__ __launch_bounds__(256) void ln_kernel(
    const float* __restrict__ hin, const float* __restrict__ g,
    const float* __restrict__ bt, u16* __restrict__ xout, float* __restrict__ fout)
{
  const int row = blockIdx.x * 4 + (threadIdx.x >> 6);
  const int lane = threadIdx.x & 63;
  const float* hr = hin + (size_t)row * 768;
  const float4 va = *(const float4*)(hr + lane * 4);
  const float4 vb = *(const float4*)(hr + 256 + lane * 4);
  const float4 vc = *(const float4*)(hr + 512 + lane * 4);
  float s  = va.x + va.y + va.z + va.w + vb.x + vb.y + vb.z + vb.w + vc.x + vc.y + vc.z + vc.w;
  float s2 = va.x * va.x + va.y * va.y + va.z * va.z + va.w * va.w
           + vb.x * vb.x + vb.y * vb.y + vb.z * vb.z + vb.w * vb.w
           + vc.x * vc.x + vc.y * vc.y + vc.z * vc.z + vc.w * vc.w;
#pragma unroll
  for (int mk = 1; mk < 64; mk <<= 1) { s += __shfl_xor(s, mk, 64); s2 += __shfl_xor(s2, mk, 64); }
  const float mean = s * (1.f / 768.f);
  const float rstd = rsqrtf(s2 * (1.f / 768.f) - mean * mean + 1e-6f);
#pragma unroll
  for (int j = 0; j < 3; ++j) {
    const int c = j * 256 + lane * 4;
    const float4 x4 = (j == 0) ? va : ((j == 1) ? vb : vc);
    const float4 g4 = *(const float4*)(g + c);
    const float4 b4 = *(const float4*)(bt + c);
    const float o0 = (x4.x - mean) * rstd * g4.x + b4.x;
    const float o1 = (x4.y - mean) * rstd * g4.y + b4.y;
    const float o2 = (x4.z - mean) * rstd * g4.z + b4.z;
    const float o3 = (x4.w - mean) * rstd * g4.w + b4.w;
    ushort4 ub; ub.x = f2bf(o0); ub.y = f2bf(o1); ub.z = f2bf(o2); ub.w = f2bf(o3);
    *(ushort4*)&xout[(size_t)row * 768 + c] = ub;
    if (FOUT) {
      float4 f4; f4.x = o0; f4.y = o1; f4.z = o2; f4.w = o3;
      *(float4*)&fout[(size_t)row * 768 + c] = f4;
    }
  }
}

// ---------------------------------------------------------------- GEMM
// C[M,N] = A[M,lda(bf16)] * BT[N,K(bf16)]^T, 128x128 tile, BK=32,
// 4 waves (2x2 of 64x64), global_load_lds staging, 16x16x32 bf16 MFMA.
// EPI: 0 bias->bf16 | 1 bias+resid->f32 | 2 bias+gelu->bf16 | 3 bias->f32
template<int EPI>
__global__ __launch_bounds__(256) void gemm_kernel(
    const u16* __restrict__ A, int lda, const u16* __restrict__ BT,
    const float* __restrict__ bias, const float* __restrict__ resid,
    void* __restrict__ outp, int M, int N, int K)
{
  __shared__ __align__(16) u16 sA[4096];  // 128 x 32 (two 64x32 halves)
  __shared__ __align__(16) u16 sB[4096];  // 128 x 32
  const int tid = threadIdx.x, lane = tid & 63, wid = tid >> 6;
  const int wr = wid >> 1, wc = wid & 1;
  const int m0 = blockIdx.y * 128, n0 = blockIdx.x * 128;
  const int l15 = lane & 15, l4 = lane >> 4;

  f32x4 acc[4][4];
#pragma unroll
  for (int i = 0; i < 4; ++i)
#pragma unroll
    for (int j = 0; j < 4; ++j) acc[i][j] = (f32x4){0.f, 0.f, 0.f, 0.f};

  // staging: thread t covers 16B chunk (row=t>>2, off=(t&3)*16B) of each half.
  // wave w lanes land at sX + w*512 + lane*8 u16 == row-major [64][32].
  const char* gA0 = (const char*)(A + (size_t)(m0 + (tid >> 2)) * lda + (tid & 3) * 8);
  const char* gA1 = (const char*)(A + (size_t)(m0 + 64 + (tid >> 2)) * lda + (tid & 3) * 8);
  const char* gB0 = (const char*)(BT + (size_t)(n0 + (tid >> 2)) * K + (tid & 3) * 8);
  const char* gB1 = (const char*)(BT + (size_t)(n0 + 64 + (tid >> 2)) * K + (tid & 3) * 8);
  u16* lA0 = sA + wid * 512;  u16* lA1 = sA + 2048 + wid * 512;
  u16* lB0 = sB + wid * 512;  u16* lB1 = sB + 2048 + wid * 512;

  const int arow = wr * 64 + l15, brow = wc * 64 + l15, koff = l4 * 8;

  for (int kt = 0; kt < K; kt += 32) {
    __syncthreads();                       // prev-iter LDS reads done
    glds16(gA0, lA0); glds16(gA1, lA1);
    glds16(gB0, lB0); glds16(gB1, lB1);
    gA0 += 64; gA1 += 64; gB0 += 64; gB1 += 64;   // advance 32 bf16
    __syncthreads();                       // vmcnt(0) drain -> tiles ready
    short8 af[4], bfv[4];
#pragma unroll
    for (int i = 0; i < 4; ++i) af[i] = *(const short8*)&sA[(arow + i * 16) * 32 + koff];
#pragma unroll
    for (int j = 0; j < 4; ++j) bfv[j] = *(const short8*)&sB[(brow + j * 16) * 32 + koff];
#pragma unroll
    for (int i = 0; i < 4; ++i)
#pragma unroll
      for (int j = 0; j < 4; ++j)
        acc[i][j] = mfma_bf16(af[i], bfv[j], acc[i][j]);
  }

  const int r0 = m0 + wr * 64 + l4 * 4;
  const int c0 = n0 + wc * 64 + l15;
#pragma unroll
  for (int i = 0; i < 4; ++i) {
#pragma unroll
    for (int j = 0; j < 4; ++j) {
      const int col = c0 + j * 16;
      const float bv = bias[col];
#pragma unroll
      for (int e = 0; e < 4; ++e) {
        const int row = r0 + i * 16 + e;
        float val = acc[i][j][e] + bv;
        if constexpr (EPI == 0) {
          ((u16*)outp)[(size_t)row * N + col] = f2bf(val);
        } else if constexpr (EPI == 1) {
          ((float*)outp)[(size_t)row * N + col] = val + resid[(size_t)row * N + col];
        } else if constexpr (EPI == 2) {
          ((u16*)outp)[(size_t)row * N + col] = f2bf(gelu_tanh(val));
        } else {
          ((float*)outp)[(size_t)row * N + col] = val;
        }
      }
    }
  }
}

// ---------------------------------------------------------------- attention
// one block per (b,h); 4 waves, each owns 16 query rows. S=64, HD=64.
__global__ __launch_bounds__(256) void attn_kernel(
    const u16* __restrict__ q, const u16* __restrict__ k, const u16* __restrict__ v,
    const int* __restrict__ amask, u16* __restrict__ o)
{
  __shared__ __align__(16) u16 sQ[64 * 80];
  __shared__ __align__(16) u16 sK[64 * 80];
  __shared__ __align__(16) u16 sVT[64 * 80];   // V transposed: [d][key]
  __shared__ __align__(16) u16 sP[4][16 * 80]; // per-wave P tile

  const int bh = blockIdx.x;
  const int b = bh / 12;
  const int h = bh - b * 12;
  const int tid = threadIdx.x, lane = tid & 63, wid = tid >> 6;
  const int l15 = lane & 15, l4 = lane >> 4;
  const size_t base = (size_t)b * (64 * 768) + h * 64;

  // stage Q,K row-major (stride 80 u16 = conflict-free, 16B-aligned)
  for (int c = tid; c < 512; c += 256) {
    const int row = c >> 3, d0 = (c & 7) * 8;
    *(uint4*)&sQ[row * 80 + d0] = *(const uint4*)(q + base + (size_t)row * 768 + d0);
    *(uint4*)&sK[row * 80 + d0] = *(const uint4*)(k + base + (size_t)row * 768 + d0);
  }
  // stage V transposed; key = lane-contiguous so scatter writes spread banks
  for (int c = tid; c < 512; c += 256) {
    const int key = c & 63, d0 = (c >> 6) * 8;
    const uint4 t4 = *(const uint4*)(v + base + (size_t)key * 768 + d0);
    const u16* pe = (const u16*)&t4;
#pragma unroll
    for (int e = 0; e < 8; ++e) sVT[(d0 + e) * 80 + key] = pe[e];
  }
  __syncthreads();

  // scores: S = Q K^T (A-frag rows = q rows, B-frag rows = K rows)
  const int qrow = wid * 16 + l15;
  const short8 qa0 = *(const short8*)&sQ[qrow * 80 + l4 * 8];
  const short8 qa1 = *(const short8*)&sQ[qrow * 80 + 32 + l4 * 8];
  f32x4 sc[4];
#pragma unroll
  for (int jf = 0; jf < 4; ++jf) {
    sc[jf] = (f32x4){0.f, 0.f, 0.f, 0.f};
    const short8 kb0 = *(const short8*)&sK[(jf * 16 + l15) * 80 + l4 * 8];
    const short8 kb1 = *(const short8*)&sK[(jf * 16 + l15) * 80 + 32 + l4 * 8];
    sc[jf] = mfma_bf16(qa0, kb0, sc[jf]);
    sc[jf] = mfma_bf16(qa1, kb1, sc[jf]);
  }
  float mv[4];
#pragma unroll
  for (int jf = 0; jf < 4; ++jf)
    mv[jf] = (amask[b * 64 + jf * 16 + l15] == 0) ? -3.402823466e38f : 0.f;

  // softmax: row = l4*4+e (16 rows/wave), cols spread over l15 x 4 j-frags
  float rsum[4];
#pragma unroll
  for (int e = 0; e < 4; ++e) {
    const float s0 = sc[0][e] * 0.125f + mv[0];
    const float s1 = sc[1][e] * 0.125f + mv[1];
    const float s2 = sc[2][e] * 0.125f + mv[2];
    const float s3 = sc[3][e] * 0.125f + mv[3];
    float mx = fmaxf(fmaxf(s0, s1), fmaxf(s2, s3));
#pragma unroll
    for (int mk = 1; mk < 16; mk <<= 1) mx = fmaxf(mx, __shfl_xor(mx, mk, 64));
    const float p0 = __expf(s0 - mx), p1 = __expf(s1 - mx);
    const float p2 = __expf(s2 - mx), p3 = __expf(s3 - mx);
    float sm = p0 + p1 + p2 + p3;
#pragma unroll
    for (int mk = 1; mk < 16; mk <<= 1) sm += __shfl_xor(sm, mk, 64);
    rsum[e] = sm;
    const int prow = l4 * 4 + e;
    sP[wid][prow * 80 +  0 + l15] = f2bf(p0);
    sP[wid][prow * 80 + 16 + l15] = f2bf(p1);
    sP[wid][prow * 80 + 32 + l15] = f2bf(p2);
    sP[wid][prow * 80 + 48 + l15] = f2bf(p3);
  }
  // cross-lane visibility of sP within the wave: barrier (uniform ctrl flow)
  __syncthreads();

  // O = P V
  const short8 pa0 = *(const short8*)&sP[wid][l15 * 80 + l4 * 8];
  const short8 pa1 = *(const short8*)&sP[wid][l15 * 80 + 32 + l4 * 8];
#pragma unroll
  for (int jf = 0; jf < 4; ++jf) {
    f32x4 oc = (f32x4){0.f, 0.f, 0.f, 0.f};
    const short8 vb0 = *(const short8*)&sVT[(jf * 16 + l15) * 80 + l4 * 8];
    const short8 vb1 = *(const short8*)&sVT[(jf * 16 + l15) * 80 + 32 + l4 * 8];
    oc = mfma_bf16(pa0, vb0, oc);
    oc = mfma_bf16(pa1, vb1, oc);
#pragma unroll
    for (int e = 0; e < 4; ++e) {
      const int row = wid * 16 + l4 * 4 + e;
      o[base + (size_t)row * 768 + jf * 16 + l15] = f2bf(oc[e] / rsum[e]);
    }
  }
}

// ---------------------------------------------------------------- launcher
extern "C" void kernel_launch(void* const* d_in, const int* in_sizes, int n_in,
                              void* d_out, int out_size, void* d_ws, size_t ws_size,
                              hipStream_t stream)
{
  (void)in_sizes; (void)n_in; (void)out_size; (void)ws_size;
  const int*   ids  = (const int*)  d_in[0];
  const int*   am   = (const int*)  d_in[1];
  const float* tok  = (const float*)d_in[2];
  const float* pos  = (const float*)d_in[3];
  const float* ln1g = (const float*)d_in[4];
  const float* ln1b = (const float*)d_in[5];
  const float* wq   = (const float*)d_in[6];
  const float* bq   = (const float*)d_in[7];
  const float* wk   = (const float*)d_in[8];
  const float* bk   = (const float*)d_in[9];
  const float* wv   = (const float*)d_in[10];
  const float* bv   = (const float*)d_in[11];
  const float* wo   = (const float*)d_in[12];
  const float* bo   = (const float*)d_in[13];
  const float* ln2g = (const float*)d_in[14];
  const float* ln2b = (const float*)d_in[15];
  const float* w1   = (const float*)d_in[16];
  const float* b1   = (const float*)d_in[17];
  const float* w2   = (const float*)d_in[18];
  const float* b2   = (const float*)d_in[19];
  const float* flng = (const float*)d_in[20];
  const float* flnb = (const float*)d_in[21];
  const float* hw   = (const float*)d_in[22];
  const float* hb   = (const float*)d_in[23];

  char* ws = (char*)d_ws;
  size_t off = 0;
  auto alloc = [&](size_t bytes) -> char* {
    char* p = ws + off; off += (bytes + 255) & ~(size_t)255; return p;
  };
  u16* wqT = (u16*)alloc((size_t)L_ * D_ * D_ * 2);
  u16* wkT = (u16*)alloc((size_t)L_ * D_ * D_ * 2);
  u16* wvT = (u16*)alloc((size_t)L_ * D_ * D_ * 2);
  u16* woT = (u16*)alloc((size_t)L_ * D_ * D_ * 2);
  u16* w1T = (u16*)alloc((size_t)L_ * D_ * F_ * 2);
  u16* w2T = (u16*)alloc((size_t)L_ * D_ * F_ * 2);
  u16* hwT = (u16*)alloc((size_t)D_ * P_ * 2);
  float* h = (float*)alloc((size_t)M_ * D_ * 4);
  u16* xb  = (u16*)alloc((size_t)M_ * D_ * 2);
  u16* qb  = (u16*)alloc((size_t)M_ * D_ * 2);
  u16* kb  = (u16*)alloc((size_t)M_ * D_ * 2);
  u16* vb  = (u16*)alloc((size_t)M_ * D_ * 2);
  u16* ob  = (u16*)alloc((size_t)M_ * D_ * 2);
  u16* m1  = (u16*)alloc((size_t)M_ * F_ * 2);

  const dim3 tb32(32, 8);
  wtrans_kernel<<<dim3(24, 24, 12), tb32, 0, stream>>>(wq, wqT, 768, 768);
  wtrans_kernel<<<dim3(24, 24, 12), tb32, 0, stream>>>(wk, wkT, 768, 768);
  wtrans_kernel<<<dim3(24, 24, 12), tb32, 0, stream>>>(wv, wvT, 768, 768);
  wtrans_kernel<<<dim3(24, 24, 12), tb32, 0, stream>>>(wo, woT, 768, 768);
  wtrans_kernel<<<dim3(96, 24, 12), tb32, 0, stream>>>(w1, w1T, 768, 3072);
  wtrans_kernel<<<dim3(24, 96, 12), tb32, 0, stream>>>(w2, w2T, 3072, 768);
  wtrans_kernel<<<dim3(24, 24, 1),  tb32, 0, stream>>>(hw, hwT, 768, 768);

  embed_kernel<<<12288, 256, 0, stream>>>(ids, tok, pos, h);

  for (int l = 0; l < 12; ++l) {
    ln_kernel<false><<<4096, 256, 0, stream>>>(h, ln1g + l * 768, ln1b + l * 768, xb, nullptr);
    gemm_kernel<0><<<dim3(6, 128), 256, 0, stream>>>(xb, 768, wqT + (size_t)l * 589824, bq + l * 768, nullptr, qb, M_, 768, 768);
    gemm_kernel<0><<<dim3(6, 128), 256, 0, stream>>>(xb, 768, wkT + (size_t)l * 589824, bk + l * 768, nullptr, kb, M_, 768, 768);
    gemm_kernel<0><<<dim3(6, 128), 256, 0, stream>>>(xb, 768, wvT + (size_t)l * 589824, bv + l * 768, nullptr, vb, M_, 768, 768);
    attn_kernel<<<3072, 256, 0, stream>>>(qb, kb, vb, am, ob);
    gemm_kernel<1><<<dim3(6, 128), 256, 0, stream>>>(ob, 768, woT + (size_t)l * 589824, bo + l * 768, h, h, M_, 768, 768);
    ln_kernel<false><<<4096, 256, 0, stream>>>(h, ln2g + l * 768, ln2b + l * 768, xb, nullptr);
    gemm_kernel<2><<<dim3(24, 128), 256, 0, stream>>>(xb, 768, w1T + (size_t)l * 2359296, b1 + l * 3072, nullptr, m1, M_, 3072, 768);
    gemm_kernel<1><<<dim3(6, 128), 256, 0, stream>>>(m1, 3072, w2T + (size_t)l * 2359296, b2 + l * 768, h, h, M_, 768, 3072);
  }

  ln_kernel<true><<<4096, 256, 0, stream>>>(h, flng, flnb, xb, (float*)d_out);
  // head on the s==63 rows via lda trick (row r of A = token r*64+63)
  gemm_kernel<3><<<dim3(6, 2), 256, 0, stream>>>(xb + 63 * 768, 64 * 768, hwT, hb, nullptr,
                                                 (float*)d_out + (size_t)M_ * D_, 256, 768, 768);
}

// Round 3
// 5417.580 us; speedup vs baseline: 1.2033x; 1.2033x over previous
//
#include <hip/hip_runtime.h>
#include <hip/hip_bf16.h>

typedef __attribute__((ext_vector_type(8))) short short8;
typedef __attribute__((ext_vector_type(4))) float f32x4;
typedef unsigned short u16;
typedef unsigned int u32;

#define L_ 12
#define D_ 768
#define F_ 3072
#define M_ 16384   // B*S
#define P_ 768
#define NQKV 2304  // 3*768

__device__ __forceinline__ u16 f2bf(float f) {
  __hip_bfloat16 h = __float2bfloat16(f);
  return __builtin_bit_cast(u16, h);
}

__device__ __forceinline__ f32x4 mfma_bf16(short8 a, short8 b, f32x4 c) {
  return __builtin_amdgcn_mfma_f32_16x16x32_bf16(a, b, c, 0, 0, 0);
}

__device__ __forceinline__ float gelu_tanh(float x) {
  float u = 0.7978845608028654f * (x + 0.044715f * x * x * x);
  float e = __expf(2.0f * u);
  float t = 1.0f - 2.0f / (e + 1.0f);   // tanh(u), safe at +-inf
  return 0.5f * x * (1.0f + t);
}

__device__ __forceinline__ void glds16(const void* g, void* l) {
  __builtin_amdgcn_global_load_lds(
      (const __attribute__((address_space(1))) u32*)g,
      (__attribute__((address_space(3))) u32*)l, 16, 0, 0);
}

// ---------------------------------------------------------------- transpose+cvt
// src fp32 [z][R][C] -> dst bf16 [z(dzs)][C][R]
__global__ __launch_bounds__(256) void wtrans_kernel(
    const float* __restrict__ src, u16* __restrict__ dst, int R, int C, size_t dzs)
{
  __shared__ float tile[32][33];
  const float* s = src + (size_t)blockIdx.z * R * C;
  u16* d = dst + (size_t)blockIdx.z * dzs;
  const int c0 = blockIdx.x * 32, r0 = blockIdx.y * 32;
  const int tx = threadIdx.x, ty = threadIdx.y;   // (32,8)
#pragma unroll
  for (int i = 0; i < 32; i += 8)
    tile[ty + i][tx] = s[(size_t)(r0 + ty + i) * C + c0 + tx];
  __syncthreads();
#pragma unroll
  for (int i = 0; i < 32; i += 8)
    d[(size_t)(c0 + ty + i) * R + r0 + tx] = f2bf(tile[tx][ty + i]);
}

// ---------------------------------------------------------------- fused qkv bias
__global__ __launch_bounds__(256) void fusebias_kernel(
    const float* __restrict__ bq, const float* __restrict__ bk,
    const float* __restrict__ bv, float* __restrict__ out)
{
  const int i = blockIdx.x * 256 + threadIdx.x;   // 12*2304
  if (i >= L_ * NQKV) return;
  const int l = i / NQKV, c = i - l * NQKV;
  float v;
  if (c < 768) v = bq[l * 768 + c];
  else if (c < 1536) v = bk[l * 768 + c - 768];
  else v = bv[l * 768 + c - 1536];
  out[i] = v;
}

// ---------------------------------------------------------------- embedding
__global__ __launch_bounds__(256) void embed_kernel(
    const int* __restrict__ ids, const float* __restrict__ tok,
    const float* __restrict__ pos, float* __restrict__ h)
{
  const int idx = blockIdx.x * 256 + threadIdx.x;  // 16384*192 float4 slots
  const int t = idx / 192;
  const int c = (idx - t * 192) * 4;
  const int s = t & 63;
  const int id = ids[t];
  const float4 te = *(const float4*)(tok + (size_t)id * 768 + c);
  const float4 pe = *(const float4*)(pos + (size_t)s * 768 + c);
  float4 r; r.x = te.x + pe.x; r.y = te.y + pe.y; r.z = te.z + pe.z; r.w = te.w + pe.w;
  *(float4*)&h[(size_t)t * 768 + c] = r;
}

// ---------------------------------------------------------------- layernorm
template<bool FOUT>
__global__ __launch_bounds__(256) void ln_kernel(
    const float* __restrict__ hin, const float* __restrict__ g,
    const float* __restrict__ bt, u16* __restrict__ xout, float* __restrict__ fout)
{
  const int row = blockIdx.x * 4 + (threadIdx.x >> 6);
  const int lane = threadIdx.x & 63;
  const float* hr = hin + (size_t)row * 768;
  const float4 va = *(const float4*)(hr + lane * 4);
  const float4 vb = *(const float4*)(hr + 256 + lane * 4);
  const float4 vc = *(const float4*)(hr + 512 + lane * 4);
  float s  = va.x + va.y + va.z + va.w + vb.x + vb.y + vb.z + vb.w + vc.x + vc.y + vc.z + vc.w;
  float s2 = va.x * va.x + va.y * va.y + va.z * va.z + va.w * va.w
           + vb.x * vb.x + vb.y * vb.y + vb.z * vb.z + vb.w * vb.w
           + vc.x * vc.x + vc.y * vc.y + vc.z * vc.z + vc.w * vc.w;
#pragma unroll
  for (int mk = 1; mk < 64; mk <<= 1) { s += __shfl_xor(s, mk, 64); s2 += __shfl_xor(s2, mk, 64); }
  const float mean = s * (1.f / 768.f);
  const float rstd = rsqrtf(s2 * (1.f / 768.f) - mean * mean + 1e-6f);
#pragma unroll
  for (int j = 0; j < 3; ++j) {
    const int c = j * 256 + lane * 4;
    const float4 x4 = (j == 0) ? va : ((j == 1) ? vb : vc);
    const float4 g4 = *(const float4*)(g + c);
    const float4 b4 = *(const float4*)(bt + c);
    const float o0 = (x4.x - mean) * rstd * g4.x + b4.x;
    const float o1 = (x4.y - mean) * rstd * g4.y + b4.y;
    const float o2 = (x4.z - mean) * rstd * g4.z + b4.z;
    const float o3 = (x4.w - mean) * rstd * g4.w + b4.w;
    ushort4 ub; ub.x = f2bf(o0); ub.y = f2bf(o1); ub.z = f2bf(o2); ub.w = f2bf(o3);
    *(ushort4*)&xout[(size_t)row * 768 + c] = ub;
    if (FOUT) {
      float4 f4; f4.x = o0; f4.y = o1; f4.z = o2; f4.w = o3;
      *(float4*)&fout[(size_t)row * 768 + c] = f4;
    }
  }
}

// ---------------------------------------------------------------- GEMM
// C[M,N] = A[M,lda] * BT[N,K]^T (bf16), 128x128 tile, BK=32, 4 waves (2x2).
// 2-phase double-buffered LDS: stage(t+1) issued BEFORE compute(t); one
// barrier per K-step (its vmcnt drain lands the prefetch). XCD-bijective
// block remap for L2 locality (m204 formula).
// EPI: 0 bias->bf16 | 1 bias+resid->f32 | 2 bias+gelu->bf16 | 3 bias->f32
template<int EPI>
__global__ __launch_bounds__(256) void gemm_kernel(
    const u16* __restrict__ A, int lda, const u16* __restrict__ BT,
    const float* __restrict__ bias, const float* __restrict__ resid,
    void* __restrict__ outp, int M, int N, int K)
{
  __shared__ __align__(16) u16 sA[2][4096];  // 2 x (128x32)
  __shared__ __align__(16) u16 sB[2][4096];
  const int tid = threadIdx.x, lane = tid & 63, wid = tid >> 6;
  const int wr = wid >> 1, wc = wid & 1;
  const int l15 = lane & 15, l4 = lane >> 4;

  // bijective XCD remap: chunk the logical tile space per XCD
  const int nbx = gridDim.x;
  const int nwg = nbx * gridDim.y;
  const int orig = blockIdx.x + nbx * blockIdx.y;
  const int q8 = nwg >> 3, r8 = nwg & 7;
  const int xcd = orig & 7, idx = orig >> 3;
  const int wgid = (xcd < r8 ? xcd * (q8 + 1) : r8 * (q8 + 1) + (xcd - r8) * q8) + idx;
  const int m0 = (wgid / nbx) * 128;
  const int n0 = (wgid - (wgid / nbx) * nbx) * 128;

  f32x4 acc[4][4];
#pragma unroll
  for (int i = 0; i < 4; ++i)
#pragma unroll
    for (int j = 0; j < 4; ++j) acc[i][j] = (f32x4){0.f, 0.f, 0.f, 0.f};

  const char* gA0 = (const char*)(A + (size_t)(m0 + (tid >> 2)) * lda + (tid & 3) * 8);
  const char* gA1 = (const char*)(A + (size_t)(m0 + 64 + (tid >> 2)) * lda + (tid & 3) * 8);
  const char* gB0 = (const char*)(BT + (size_t)(n0 + (tid >> 2)) * K + (tid & 3) * 8);
  const char* gB1 = (const char*)(BT + (size_t)(n0 + 64 + (tid >> 2)) * K + (tid & 3) * 8);
  const int lofs = wid * 512;

  auto stage = [&](int buf) {
    glds16(gA0, sA[buf] + lofs); glds16(gA1, sA[buf] + 2048 + lofs);
    glds16(gB0, sB[buf] + lofs); glds16(gB1, sB[buf] + 2048 + lofs);
    gA0 += 64; gA1 += 64; gB0 += 64; gB1 += 64;   // advance 32 bf16
  };

  const int arow = wr * 64 + l15, brow = wc * 64 + l15, koff = l4 * 8;
  const int niter = K >> 5;

  stage(0);
  __syncthreads();                    // drain vmcnt(0): buf0 ready

#pragma unroll 2
  for (int t = 0; t < niter - 1; ++t) {
    const int cur = t & 1;
    stage(cur ^ 1);                   // prefetch next tile (in flight during MFMA)
    short8 af[4], bfv[4];
#pragma unroll
    for (int i = 0; i < 4; ++i) af[i] = *(const short8*)&sA[cur][(arow + i * 16) * 32 + koff];
#pragma unroll
    for (int j = 0; j < 4; ++j) bfv[j] = *(const short8*)&sB[cur][(brow + j * 16) * 32 + koff];
#pragma unroll
    for (int i = 0; i < 4; ++i)
#pragma unroll
      for (int j = 0; j < 4; ++j)
        acc[i][j] = mfma_bf16(af[i], bfv[j], acc[i][j]);
    __syncthreads();                  // reads of cur done + prefetch landed
  }
  {
    const int cur = (niter - 1) & 1;
    short8 af[4], bfv[4];
#pragma unroll
    for (int i = 0; i < 4; ++i) af[i] = *(const short8*)&sA[cur][(arow + i * 16) * 32 + koff];
#pragma unroll
    for (int j = 0; j < 4; ++j) bfv[j] = *(const short8*)&sB[cur][(brow + j * 16) * 32 + koff];
#pragma unroll
    for (int i = 0; i < 4; ++i)
#pragma unroll
      for (int j = 0; j < 4; ++j)
        acc[i][j] = mfma_bf16(af[i], bfv[j], acc[i][j]);
  }

  const int r0 = m0 + wr * 64 + l4 * 4;
  const int c0 = n0 + wc * 64 + l15;
#pragma unroll
  for (int i = 0; i < 4; ++i) {
#pragma unroll
    for (int j = 0; j < 4; ++j) {
      const int col = c0 + j * 16;
      const float bv = bias[col];
#pragma unroll
      for (int e = 0; e < 4; ++e) {
        const int row = r0 + i * 16 + e;
        float val = acc[i][j][e] + bv;
        if constexpr (EPI == 0) {
          ((u16*)outp)[(size_t)row * N + col] = f2bf(val);
        } else if constexpr (EPI == 1) {
          ((float*)outp)[(size_t)row * N + col] = val + resid[(size_t)row * N + col];
        } else if constexpr (EPI == 2) {
          ((u16*)outp)[(size_t)row * N + col] = f2bf(gelu_tanh(val));
        } else {
          ((float*)outp)[(size_t)row * N + col] = val;
        }
      }
    }
  }
}

// ---------------------------------------------------------------- attention
// one block per (b,h); 4 waves x 16 query rows. Reads packed qkv [M][2304].
__global__ __launch_bounds__(256) void attn_kernel(
    const u16* __restrict__ qkv, const int* __restrict__ amask, u16* __restrict__ o)
{
  __shared__ __align__(16) u16 sQ[64 * 80];
  __shared__ __align__(16) u16 sK[64 * 80];
  __shared__ __align__(16) u16 sVT[64 * 80];   // V transposed: [d][key]
  __shared__ __align__(16) u16 sP[4][16 * 80]; // per-wave P tile

  const int bh = blockIdx.x;
  const int b = bh / 12;
  const int h = bh - b * 12;
  const int tid = threadIdx.x, lane = tid & 63, wid = tid >> 6;
  const int l15 = lane & 15, l4 = lane >> 4;
  const size_t base = (size_t)b * (64 * NQKV) + h * 64;   // q cols; k +768; v +1536
  const size_t obase = (size_t)b * (64 * 768) + h * 64;

  for (int c = tid; c < 512; c += 256) {
    const int row = c >> 3, d0 = (c & 7) * 8;
    *(uint4*)&sQ[row * 80 + d0] = *(const uint4*)(qkv + base + (size_t)row * NQKV + d0);
    *(uint4*)&sK[row * 80 + d0] = *(const uint4*)(qkv + base + 768 + (size_t)row * NQKV + d0);
  }
  for (int c = tid; c < 512; c += 256) {
    const int key = c & 63, d0 = (c >> 6) * 8;
    const uint4 t4 = *(const uint4*)(qkv + base + 1536 + (size_t)key * NQKV + d0);
    const u16* pe = (const u16*)&t4;
#pragma unroll
    for (int e = 0; e < 8; ++e) sVT[(d0 + e) * 80 + key] = pe[e];
  }
  __syncthreads();

  const int qrow = wid * 16 + l15;
  const short8 qa0 = *(const short8*)&sQ[qrow * 80 + l4 * 8];
  const short8 qa1 = *(const short8*)&sQ[qrow * 80 + 32 + l4 * 8];
  f32x4 sc[4];
#pragma unroll
  for (int jf = 0; jf < 4; ++jf) {
    sc[jf] = (f32x4){0.f, 0.f, 0.f, 0.f};
    const short8 kb0 = *(const short8*)&sK[(jf * 16 + l15) * 80 + l4 * 8];
    const short8 kb1 = *(const short8*)&sK[(jf * 16 + l15) * 80 + 32 + l4 * 8];
    sc[jf] = mfma_bf16(qa0, kb0, sc[jf]);
    sc[jf] = mfma_bf16(qa1, kb1, sc[jf]);
  }
  float mv[4];
#pragma unroll
  for (int jf = 0; jf < 4; ++jf)
    mv[jf] = (amask[b * 64 + jf * 16 + l15] == 0) ? -3.402823466e38f : 0.f;

  float rsum[4];
#pragma unroll
  for (int e = 0; e < 4; ++e) {
    const float s0 = sc[0][e] * 0.125f + mv[0];
    const float s1 = sc[1][e] * 0.125f + mv[1];
    const float s2 = sc[2][e] * 0.125f + mv[2];
    const float s3 = sc[3][e] * 0.125f + mv[3];
    float mx = fmaxf(fmaxf(s0, s1), fmaxf(s2, s3));
#pragma unroll
    for (int mk = 1; mk < 16; mk <<= 1) mx = fmaxf(mx, __shfl_xor(mx, mk, 64));
    const float p0 = __expf(s0 - mx), p1 = __expf(s1 - mx);
    const float p2 = __expf(s2 - mx), p3 = __expf(s3 - mx);
    float sm = p0 + p1 + p2 + p3;
#pragma unroll
    for (int mk = 1; mk < 16; mk <<= 1) sm += __shfl_xor(sm, mk, 64);
    rsum[e] = sm;
    const int prow = l4 * 4 + e;
    sP[wid][prow * 80 +  0 + l15] = f2bf(p0);
    sP[wid][prow * 80 + 16 + l15] = f2bf(p1);
    sP[wid][prow * 80 + 32 + l15] = f2bf(p2);
    sP[wid][prow * 80 + 48 + l15] = f2bf(p3);
  }
  __syncthreads();

  const short8 pa0 = *(const short8*)&sP[wid][l15 * 80 + l4 * 8];
  const short8 pa1 = *(const short8*)&sP[wid][l15 * 80 + 32 + l4 * 8];
#pragma unroll
  for (int jf = 0; jf < 4; ++jf) {
    f32x4 oc = (f32x4){0.f, 0.f, 0.f, 0.f};
    const short8 vb0 = *(const short8*)&sVT[(jf * 16 + l15) * 80 + l4 * 8];
    const short8 vb1 = *(const short8*)&sVT[(jf * 16 + l15) * 80 + 32 + l4 * 8];
    oc = mfma_bf16(pa0, vb0, oc);
    oc = mfma_bf16(pa1, vb1, oc);
#pragma unroll
    for (int e = 0; e < 4; ++e) {
      const int row = wid * 16 + l4 * 4 + e;
      o[obase + (size_t)row * 768 + jf * 16 + l15] = f2bf(oc[e] / rsum[e]);
    }
  }
}

// ---------------------------------------------------------------- launcher
extern "C" void kernel_launch(void* const* d_in, const int* in_sizes, int n_in,
                              void* d_out, int out_size, void* d_ws, size_t ws_size,
                              hipStream_t stream)
{
  (void)in_sizes; (void)n_in; (void)out_size; (void)ws_size;
  const int*   ids  = (const int*)  d_in[0];
  const int*   am   = (const int*)  d_in[1];
  const float* tok  = (const float*)d_in[2];
  const float* pos  = (const float*)d_in[3];
  const float* ln1g = (const float*)d_in[4];
  const float* ln1b = (const float*)d_in[5];
  const float* wq   = (const float*)d_in[6];
  const float* bq   = (const float*)d_in[7];
  const float* wk   = (const float*)d_in[8];
  const float* bk   = (const float*)d_in[9];
  const float* wv   = (const float*)d_in[10];
  const float* bv   = (const float*)d_in[11];
  const float* wo   = (const float*)d_in[12];
  const float* bo   = (const float*)d_in[13];
  const float* ln2g = (const float*)d_in[14];
  const float* ln2b = (const float*)d_in[15];
  const float* w1   = (const float*)d_in[16];
  const float* b1   = (const float*)d_in[17];
  const float* w2   = (const float*)d_in[18];
  const float* b2   = (const float*)d_in[19];
  const float* flng = (const float*)d_in[20];
  const float* flnb = (const float*)d_in[21];
  const float* hw   = (const float*)d_in[22];
  const float* hb   = (const float*)d_in[23];

  char* ws = (char*)d_ws;
  size_t off = 0;
  auto alloc = [&](size_t bytes) -> char* {
    char* p = ws + off; off += (bytes + 255) & ~(size_t)255; return p;
  };
  u16* wqkvT = (u16*)alloc((size_t)L_ * NQKV * D_ * 2);   // [L][2304][768]
  u16* woT = (u16*)alloc((size_t)L_ * D_ * D_ * 2);
  u16* w1T = (u16*)alloc((size_t)L_ * D_ * F_ * 2);
  u16* w2T = (u16*)alloc((size_t)L_ * D_ * F_ * 2);
  u16* hwT = (u16*)alloc((size_t)D_ * P_ * 2);
  float* bqkv = (float*)alloc((size_t)L_ * NQKV * 4);
  float* h = (float*)alloc((size_t)M_ * D_ * 4);
  u16* xb   = (u16*)alloc((size_t)M_ * D_ * 2);
  u16* qkvb = (u16*)alloc((size_t)M_ * NQKV * 2);
  u16* ob   = (u16*)alloc((size_t)M_ * D_ * 2);
  u16* m1   = (u16*)alloc((size_t)M_ * F_ * 2);

  const dim3 tb32(32, 8);
  const size_t LQKV = (size_t)NQKV * D_;   // per-layer fused stride
  wtrans_kernel<<<dim3(24, 24, 12), tb32, 0, stream>>>(wq, wqkvT,            768, 768, LQKV);
  wtrans_kernel<<<dim3(24, 24, 12), tb32, 0, stream>>>(wk, wqkvT + 589824,   768, 768, LQKV);
  wtrans_kernel<<<dim3(24, 24, 12), tb32, 0, stream>>>(wv, wqkvT + 1179648,  768, 768, LQKV);
  wtrans_kernel<<<dim3(24, 24, 12), tb32, 0, stream>>>(wo, woT, 768, 768, (size_t)D_ * D_);
  wtrans_kernel<<<dim3(96, 24, 12), tb32, 0, stream>>>(w1, w1T, 768, 3072, (size_t)D_ * F_);
  wtrans_kernel<<<dim3(24, 96, 12), tb32, 0, stream>>>(w2, w2T, 3072, 768, (size_t)D_ * F_);
  wtrans_kernel<<<dim3(24, 24, 1),  tb32, 0, stream>>>(hw, hwT, 768, 768, (size_t)D_ * P_);
  fusebias_kernel<<<108, 256, 0, stream>>>(bq, bk, bv, bqkv);

  embed_kernel<<<12288, 256, 0, stream>>>(ids, tok, pos, h);

  for (int l = 0; l < 12; ++l) {
    ln_kernel<false><<<4096, 256, 0, stream>>>(h, ln1g + l * 768, ln1b + l * 768, xb, nullptr);
    gemm_kernel<0><<<dim3(18, 128), 256, 0, stream>>>(xb, 768, wqkvT + (size_t)l * LQKV,
                                                      bqkv + l * NQKV, nullptr, qkvb, M_, NQKV, 768);
    attn_kernel<<<3072, 256, 0, stream>>>(qkvb, am, ob);
    gemm_kernel<1><<<dim3(6, 128), 256, 0, stream>>>(ob, 768, woT + (size_t)l * 589824, bo + l * 768, h, h, M_, 768, 768);
    ln_kernel<false><<<4096, 256, 0, stream>>>(h, ln2g + l * 768, ln2b + l * 768, xb, nullptr);
    gemm_kernel<2><<<dim3(24, 128), 256, 0, stream>>>(xb, 768, w1T + (size_t)l * 2359296, b1 + l * 3072, nullptr, m1, M_, 3072, 768);
    gemm_kernel<1><<<dim3(6, 128), 256, 0, stream>>>(m1, 3072, w2T + (size_t)l * 2359296, b2 + l * 768, h, h, M_, 768, 3072);
  }

  ln_kernel<true><<<4096, 256, 0, stream>>>(h, flng, flnb, xb, (float*)d_out);
  gemm_kernel<3><<<dim3(6, 2), 256, 0, stream>>>(xb + 63 * 768, 64 * 768, hwT, hb, nullptr,
                                                 (float*)d_out + (size_t)M_ * D_, 256, 768, 768);
}

// Round 5
// 5063.165 us; speedup vs baseline: 1.2875x; 1.0700x over previous
//
#include <hip/hip_runtime.h>
#include <hip/hip_bf16.h>

typedef __attribute__((ext_vector_type(8))) short short8;
typedef __attribute__((ext_vector_type(4))) float f32x4;
typedef unsigned short u16;
typedef unsigned int u32;

#define L_ 12
#define D_ 768
#define F_ 3072
#define M_ 16384   // B*S
#define P_ 768
#define NQKV 2304  // 3*768

__device__ __forceinline__ u16 f2bf(float f) {
  __hip_bfloat16 h = __float2bfloat16(f);
  return __builtin_bit_cast(u16, h);
}

__device__ __forceinline__ f32x4 mfma_bf16(short8 a, short8 b, f32x4 c) {
  return __builtin_amdgcn_mfma_f32_16x16x32_bf16(a, b, c, 0, 0, 0);
}

__device__ __forceinline__ float gelu_tanh(float x) {
  float u = 0.7978845608028654f * (x + 0.044715f * x * x * x);
  float e = __expf(2.0f * u);
  float t = 1.0f - 2.0f / (e + 1.0f);   // tanh(u), safe at +-inf
  return 0.5f * x * (1.0f + t);
}

__device__ __forceinline__ void glds16(const void* g, void* l) {
  __builtin_amdgcn_global_load_lds(
      (const __attribute__((address_space(1))) u32*)g,
      (__attribute__((address_space(3))) u32*)l, 16, 0, 0);
}

#define LGKM0 do { asm volatile("s_waitcnt lgkmcnt(0)" ::: "memory"); \
                   __builtin_amdgcn_sched_barrier(0); } while (0)
#define VM0   asm volatile("s_waitcnt vmcnt(0)" ::: "memory")

// ---------------------------------------------------------------- transpose+cvt
// src fp32 [z][R][C] -> dst bf16 [z(dzs)][C][R]
__global__ __launch_bounds__(256) void wtrans_kernel(
    const float* __restrict__ src, u16* __restrict__ dst, int R, int C, size_t dzs)
{
  __shared__ float tile[32][33];
  const float* s = src + (size_t)blockIdx.z * R * C;
  u16* d = dst + (size_t)blockIdx.z * dzs;
  const int c0 = blockIdx.x * 32, r0 = blockIdx.y * 32;
  const int tx = threadIdx.x, ty = threadIdx.y;   // (32,8)
#pragma unroll
  for (int i = 0; i < 32; i += 8)
    tile[ty + i][tx] = s[(size_t)(r0 + ty + i) * C + c0 + tx];
  __syncthreads();
#pragma unroll
  for (int i = 0; i < 32; i += 8)
    d[(size_t)(c0 + ty + i) * R + r0 + tx] = f2bf(tile[tx][ty + i]);
}

// ---------------------------------------------------------------- fused qkv bias
__global__ __launch_bounds__(256) void fusebias_kernel(
    const float* __restrict__ bq, const float* __restrict__ bk,
    const float* __restrict__ bv, float* __restrict__ out)
{
  const int i = blockIdx.x * 256 + threadIdx.x;   // 12*2304
  if (i >= L_ * NQKV) return;
  const int l = i / NQKV, c = i - l * NQKV;
  float v;
  if (c < 768) v = bq[l * 768 + c];
  else if (c < 1536) v = bk[l * 768 + c - 768];
  else v = bv[l * 768 + c - 1536];
  out[i] = v;
}

// ---------------------------------------------------------------- embedding
__global__ __launch_bounds__(256) void embed_kernel(
    const int* __restrict__ ids, const float* __restrict__ tok,
    const float* __restrict__ pos, float* __restrict__ h)
{
  const int idx = blockIdx.x * 256 + threadIdx.x;  // 16384*192 float4 slots
  const int t = idx / 192;
  const int c = (idx - t * 192) * 4;
  const int s = t & 63;
  const int id = ids[t];
  const float4 te = *(const float4*)(tok + (size_t)id * 768 + c);
  const float4 pe = *(const float4*)(pos + (size_t)s * 768 + c);
  float4 r; r.x = te.x + pe.x; r.y = te.y + pe.y; r.z = te.z + pe.z; r.w = te.w + pe.w;
  *(float4*)&h[(size_t)t * 768 + c] = r;
}

// ---------------------------------------------------------------- layernorm
template<bool FOUT>
__global__ __launch_bounds__(256) void ln_kernel(
    const float* __restrict__ hin, const float* __restrict__ g,
    const float* __restrict__ bt, u16* __restrict__ xout, float* __restrict__ fout)
{
  const int row = blockIdx.x * 4 + (threadIdx.x >> 6);
  const int lane = threadIdx.x & 63;
  const float* hr = hin + (size_t)row * 768;
  const float4 va = *(const float4*)(hr + lane * 4);
  const float4 vb = *(const float4*)(hr + 256 + lane * 4);
  const float4 vc = *(const float4*)(hr + 512 + lane * 4);
  float s  = va.x + va.y + va.z + va.w + vb.x + vb.y + vb.z + vb.w + vc.x + vc.y + vc.z + vc.w;
  float s2 = va.x * va.x + va.y * va.y + va.z * va.z + va.w * va.w
           + vb.x * vb.x + vb.y * vb.y + vb.z * vb.z + vb.w * vb.w
           + vc.x * vc.x + vc.y * vc.y + vc.z * vc.z + vc.w * vc.w;
#pragma unroll
  for (int mk = 1; mk < 64; mk <<= 1) { s += __shfl_xor(s, mk, 64); s2 += __shfl_xor(s2, mk, 64); }
  const float mean = s * (1.f / 768.f);
  const float rstd = rsqrtf(s2 * (1.f / 768.f) - mean * mean + 1e-6f);
#pragma unroll
  for (int j = 0; j < 3; ++j) {
    const int c = j * 256 + lane * 4;
    const float4 x4 = (j == 0) ? va : ((j == 1) ? vb : vc);
    const float4 g4 = *(const float4*)(g + c);
    const float4 b4 = *(const float4*)(bt + c);
    const float o0 = (x4.x - mean) * rstd * g4.x + b4.x;
    const float o1 = (x4.y - mean) * rstd * g4.y + b4.y;
    const float o2 = (x4.z - mean) * rstd * g4.z + b4.z;
    const float o3 = (x4.w - mean) * rstd * g4.w + b4.w;
    ushort4 ub; ub.x = f2bf(o0); ub.y = f2bf(o1); ub.z = f2bf(o2); ub.w = f2bf(o3);
    *(ushort4*)&xout[(size_t)row * 768 + c] = ub;
    if (FOUT) {
      float4 f4; f4.x = o0; f4.y = o1; f4.z = o2; f4.w = o3;
      *(float4*)&fout[(size_t)row * 768 + c] = f4;
    }
  }
}

// ---------------------------------------------------------------- GEMM 256x256 8-phase
// C[M,N] = A[M,lda] * BT[N,K]^T (bf16). BM=BN=256, BK=64, 8 waves (2Mx4N),
// per-wave output 128x64. LDS 128KB = 2 dbuf x (A 32KB + B 32KB), halves of
// 128 rows x 64 cols. T2 XOR-swizzle (granule ^= row&7) with inverse-swizzled
// global source (linear glds dest). Per K-tile: 4 phases {ds_read subtile ->
// s_barrier -> lgkmcnt(0) -> setprio+16 MFMA -> s_barrier}; all 8 prefetch
// glds issued at phase 0 into other buffer; vmcnt(0) once per K-tile (p3).
// EPI: 0 bias->bf16 | 1 bias+resid->f32 | 2 bias+gelu->bf16 | 3 bias->f32
template<int EPI>
__global__ __launch_bounds__(512, 2) void gemm256_kernel(
    const u16* __restrict__ A, int lda, const u16* __restrict__ BT,
    const float* __restrict__ bias, const float* __restrict__ resid,
    void* __restrict__ outp, int M, int N, int K)
{
  __shared__ __align__(16) char lds[131072];
  const int tid = threadIdx.x, lane = tid & 63, wid = tid >> 6;
  const int wm = wid >> 2, wn = wid & 3;
  const int l15 = lane & 15, l4 = lane >> 4;

  // bijective XCD remap
  const int nbx = gridDim.x, nwg = nbx * gridDim.y;
  const int orig = blockIdx.x + nbx * blockIdx.y;
  const int q8 = nwg >> 3, r8 = nwg & 7;
  const int xcd = orig & 7, cidx = orig >> 3;
  const int wg = (xcd < r8 ? xcd * (q8 + 1) : r8 * (q8 + 1) + (xcd - r8) * q8) + cidx;
  const int m0 = (wg / nbx) * 256;
  const int n0 = (wg - (wg / nbx) * nbx) * 256;

  f32x4 acc[8][4];
#pragma unroll
  for (int i = 0; i < 8; ++i)
#pragma unroll
    for (int j = 0; j < 4; ++j) acc[i][j] = (f32x4){0.f, 0.f, 0.f, 0.f};

  // staging: instr i covers granule g = tid + i*512 of each 16KB half.
  // LDS granule (row=g>>3, gcol=g&7) must hold global chunk (g&7)^(row&7).
  const int g1 = tid + 512;
  const int r0s = tid >> 3, r1s = g1 >> 3;
  const int c0s = (tid & 7) ^ (r0s & 7), c1s = (g1 & 7) ^ (r1s & 7);
  const int aoff0 = r0s * lda + c0s * 8, aoff1 = r1s * lda + c1s * 8;
  const int boff0 = r0s * K + c0s * 8, boff1 = r1s * K + c1s * 8;
  const u16* Abase = A + (size_t)m0 * lda;
  const u16* Bbase = BT + (size_t)n0 * K;
  const int ldsw = wid * 1024;

  auto stageTile = [&](int b, int kt) {
    const u16* Ak = Abase + kt;
    const u16* Bk = Bbase + kt;
    char* LA = lds + b * 65536;
    char* LB = LA + 32768;
    glds16(Ak + aoff0, LA + ldsw);
    glds16(Ak + aoff1, LA + 8192 + ldsw);
    glds16(Ak + 128 * lda + aoff0, LA + 16384 + ldsw);
    glds16(Ak + 128 * lda + aoff1, LA + 16384 + 8192 + ldsw);
    glds16(Bk + boff0, LB + ldsw);
    glds16(Bk + boff1, LB + 8192 + ldsw);
    glds16(Bk + 128 * K + boff0, LB + 16384 + ldsw);
    glds16(Bk + 128 * K + boff1, LB + 16384 + 8192 + ldsw);
  };

  // fragment read addressing (byte offsets into a buffer)
  const int sw = l15 & 7;
  const int cs0 = (l4 ^ sw) << 4;           // ks=0: gcol=l4
  const int cs1 = ((4 + l4) ^ sw) << 4;     // ks=1: gcol=4+l4
  const int aRdRow = wm * 16384 + l15 * 128;
  const int bRdRow = 32768 + (wn >> 1) * 16384 + ((wn & 1) * 64 + l15) * 128;

  short8 af[4][2], bn0[2][2], bn1[2][2];

  auto loadA = [&](const char* Lb, int mq) {
#pragma unroll
    for (int mf = 0; mf < 4; ++mf) {
      af[mf][0] = *(const short8*)(Lb + aRdRow + mq * 8192 + mf * 2048 + cs0);
      af[mf][1] = *(const short8*)(Lb + aRdRow + mq * 8192 + mf * 2048 + cs1);
    }
  };
  auto loadB = [&](const char* Lb, int nq, short8 (&bf)[2][2]) {
#pragma unroll
    for (int nf = 0; nf < 2; ++nf) {
      bf[nf][0] = *(const short8*)(Lb + bRdRow + nq * 4096 + nf * 2048 + cs0);
      bf[nf][1] = *(const short8*)(Lb + bRdRow + nq * 4096 + nf * 2048 + cs1);
    }
  };
  auto mmaQ = [&](int mq, int nq, short8 (&bf)[2][2]) {
#pragma unroll
    for (int mf = 0; mf < 4; ++mf)
#pragma unroll
      for (int nf = 0; nf < 2; ++nf)
#pragma unroll
        for (int ks = 0; ks < 2; ++ks)
          acc[mq * 4 + mf][nq * 2 + nf] =
              mfma_bf16(af[mf][ks], bf[nf][ks], acc[mq * 4 + mf][nq * 2 + nf]);
  };

  const int nt = K >> 6;

  auto ktile = [&](int b, int t) {
    const char* Lb = lds + b * 65536;
    // ---- p0: prefetch next tile + read A(mq0), B(nq0); MFMA Q(0,0)
    if (t + 1 < nt) stageTile(b ^ 1, (t + 1) << 6);
    loadA(Lb, 0);
    loadB(Lb, 0, bn0);
    __builtin_amdgcn_s_barrier();
    LGKM0;
    __builtin_amdgcn_s_setprio(1); mmaQ(0, 0, bn0); __builtin_amdgcn_s_setprio(0);
    __builtin_amdgcn_s_barrier();
    // ---- p1: read B(nq1); MFMA Q(0,1)
    loadB(Lb, 1, bn1);
    __builtin_amdgcn_s_barrier();
    LGKM0;
    __builtin_amdgcn_s_setprio(1); mmaQ(0, 1, bn1); __builtin_amdgcn_s_setprio(0);
    __builtin_amdgcn_s_barrier();
    // ---- p2: read A(mq1); MFMA Q(1,1)
    loadA(Lb, 1);
    __builtin_amdgcn_s_barrier();
    LGKM0;
    __builtin_amdgcn_s_setprio(1); mmaQ(1, 1, bn1); __builtin_amdgcn_s_setprio(0);
    __builtin_amdgcn_s_barrier();
    // ---- p3: MFMA Q(1,0); drain prefetch; buffer swap barrier
    __builtin_amdgcn_s_setprio(1); mmaQ(1, 0, bn0); __builtin_amdgcn_s_setprio(0);
    VM0;
    __builtin_amdgcn_s_barrier();
  };

  stageTile(0, 0);
  VM0;
  __builtin_amdgcn_s_barrier();
  for (int t = 0; t < nt; t += 2) { ktile(0, t); ktile(1, t + 1); }

  // ---- epilogue
  const int rbase = m0 + wm * 128 + l4 * 4;
  const int cbase = n0 + wn * 64 + l15;
#pragma unroll
  for (int mi = 0; mi < 8; ++mi) {
#pragma unroll
    for (int ni = 0; ni < 4; ++ni) {
      const int col = cbase + (ni >> 1) * 32 + (ni & 1) * 16;
      const float bv = bias[col];
#pragma unroll
      for (int e = 0; e < 4; ++e) {
        const int row = rbase + (mi >> 2) * 64 + (mi & 3) * 16 + e;
        float val = acc[mi][ni][e] + bv;
        if constexpr (EPI == 0) {
          ((u16*)outp)[(size_t)row * N + col] = f2bf(val);
        } else if constexpr (EPI == 1) {
          ((float*)outp)[(size_t)row * N + col] = val + resid[(size_t)row * N + col];
        } else if constexpr (EPI == 2) {
          ((u16*)outp)[(size_t)row * N + col] = f2bf(gelu_tanh(val));
        } else {
          ((float*)outp)[(size_t)row * N + col] = val;
        }
      }
    }
  }
}

// ---------------------------------------------------------------- GEMM 128x128 2-phase (head)
template<int EPI>
__global__ __launch_bounds__(256) void gemm_kernel(
    const u16* __restrict__ A, int lda, const u16* __restrict__ BT,
    const float* __restrict__ bias, const float* __restrict__ resid,
    void* __restrict__ outp, int M, int N, int K)
{
  __shared__ __align__(16) u16 sA[2][4096];
  __shared__ __align__(16) u16 sB[2][4096];
  const int tid = threadIdx.x, lane = tid & 63, wid = tid >> 6;
  const int wr = wid >> 1, wc = wid & 1;
  const int l15 = lane & 15, l4 = lane >> 4;

  const int nbx = gridDim.x;
  const int nwg = nbx * gridDim.y;
  const int orig = blockIdx.x + nbx * blockIdx.y;
  const int q8 = nwg >> 3, r8 = nwg & 7;
  const int xcd = orig & 7, idx = orig >> 3;
  const int wgid = (xcd < r8 ? xcd * (q8 + 1) : r8 * (q8 + 1) + (xcd - r8) * q8) + idx;
  const int m0 = (wgid / nbx) * 128;
  const int n0 = (wgid - (wgid / nbx) * nbx) * 128;

  f32x4 acc[4][4];
#pragma unroll
  for (int i = 0; i < 4; ++i)
#pragma unroll
    for (int j = 0; j < 4; ++j) acc[i][j] = (f32x4){0.f, 0.f, 0.f, 0.f};

  const char* gA0 = (const char*)(A + (size_t)(m0 + (tid >> 2)) * lda + (tid & 3) * 8);
  const char* gA1 = (const char*)(A + (size_t)(m0 + 64 + (tid >> 2)) * lda + (tid & 3) * 8);
  const char* gB0 = (const char*)(BT + (size_t)(n0 + (tid >> 2)) * K + (tid & 3) * 8);
  const char* gB1 = (const char*)(BT + (size_t)(n0 + 64 + (tid >> 2)) * K + (tid & 3) * 8);
  const int lofs = wid * 512;

  auto stage = [&](int buf) {
    glds16(gA0, sA[buf] + lofs); glds16(gA1, sA[buf] + 2048 + lofs);
    glds16(gB0, sB[buf] + lofs); glds16(gB1, sB[buf] + 2048 + lofs);
    gA0 += 64; gA1 += 64; gB0 += 64; gB1 += 64;
  };

  const int arow = wr * 64 + l15, brow = wc * 64 + l15, koff = l4 * 8;
  const int niter = K >> 5;

  stage(0);
  __syncthreads();

#pragma unroll 2
  for (int t = 0; t < niter - 1; ++t) {
    const int cur = t & 1;
    stage(cur ^ 1);
    short8 afv[4], bfv[4];
#pragma unroll
    for (int i = 0; i < 4; ++i) afv[i] = *(const short8*)&sA[cur][(arow + i * 16) * 32 + koff];
#pragma unroll
    for (int j = 0; j < 4; ++j) bfv[j] = *(const short8*)&sB[cur][(brow + j * 16) * 32 + koff];
#pragma unroll
    for (int i = 0; i < 4; ++i)
#pragma unroll
      for (int j = 0; j < 4; ++j)
        acc[i][j] = mfma_bf16(afv[i], bfv[j], acc[i][j]);
    __syncthreads();
  }
  {
    const int cur = (niter - 1) & 1;
    short8 afv[4], bfv[4];
#pragma unroll
    for (int i = 0; i < 4; ++i) afv[i] = *(const short8*)&sA[cur][(arow + i * 16) * 32 + koff];
#pragma unroll
    for (int j = 0; j < 4; ++j) bfv[j] = *(const short8*)&sB[cur][(brow + j * 16) * 32 + koff];
#pragma unroll
    for (int i = 0; i < 4; ++i)
#pragma unroll
      for (int j = 0; j < 4; ++j)
        acc[i][j] = mfma_bf16(afv[i], bfv[j], acc[i][j]);
  }

  const int r0 = m0 + wr * 64 + l4 * 4;
  const int c0 = n0 + wc * 64 + l15;
#pragma unroll
  for (int i = 0; i < 4; ++i) {
#pragma unroll
    for (int j = 0; j < 4; ++j) {
      const int col = c0 + j * 16;
      const float bv = bias[col];
#pragma unroll
      for (int e = 0; e < 4; ++e) {
        const int row = r0 + i * 16 + e;
        float val = acc[i][j][e] + bv;
        if constexpr (EPI == 0) {
          ((u16*)outp)[(size_t)row * N + col] = f2bf(val);
        } else if constexpr (EPI == 1) {
          ((float*)outp)[(size_t)row * N + col] = val + resid[(size_t)row * N + col];
        } else if constexpr (EPI == 2) {
          ((u16*)outp)[(size_t)row * N + col] = f2bf(gelu_tanh(val));
        } else {
          ((float*)outp)[(size_t)row * N + col] = val;
        }
      }
    }
  }
}

// ---------------------------------------------------------------- attention
__global__ __launch_bounds__(256) void attn_kernel(
    const u16* __restrict__ qkv, const int* __restrict__ amask, u16* __restrict__ o)
{
  __shared__ __align__(16) u16 sQ[64 * 80];
  __shared__ __align__(16) u16 sK[64 * 80];
  __shared__ __align__(16) u16 sVT[64 * 80];
  __shared__ __align__(16) u16 sP[4][16 * 80];

  const int bh = blockIdx.x;
  const int b = bh / 12;
  const int h = bh - b * 12;
  const int tid = threadIdx.x, lane = tid & 63, wid = tid >> 6;
  const int l15 = lane & 15, l4 = lane >> 4;
  const size_t base = (size_t)b * (64 * NQKV) + h * 64;
  const size_t obase = (size_t)b * (64 * 768) + h * 64;

  for (int c = tid; c < 512; c += 256) {
    const int row = c >> 3, d0 = (c & 7) * 8;
    *(uint4*)&sQ[row * 80 + d0] = *(const uint4*)(qkv + base + (size_t)row * NQKV + d0);
    *(uint4*)&sK[row * 80 + d0] = *(const uint4*)(qkv + base + 768 + (size_t)row * NQKV + d0);
  }
  for (int c = tid; c < 512; c += 256) {
    const int key = c & 63, d0 = (c >> 6) * 8;
    const uint4 t4 = *(const uint4*)(qkv + base + 1536 + (size_t)key * NQKV + d0);
    const u16* pe = (const u16*)&t4;
#pragma unroll
    for (int e = 0; e < 8; ++e) sVT[(d0 + e) * 80 + key] = pe[e];
  }
  __syncthreads();

  const int qrow = wid * 16 + l15;
  const short8 qa0 = *(const short8*)&sQ[qrow * 80 + l4 * 8];
  const short8 qa1 = *(const short8*)&sQ[qrow * 80 + 32 + l4 * 8];
  f32x4 sc[4];
#pragma unroll
  for (int jf = 0; jf < 4; ++jf) {
    sc[jf] = (f32x4){0.f, 0.f, 0.f, 0.f};
    const short8 kb0 = *(const short8*)&sK[(jf * 16 + l15) * 80 + l4 * 8];
    const short8 kb1 = *(const short8*)&sK[(jf * 16 + l15) * 80 + 32 + l4 * 8];
    sc[jf] = mfma_bf16(qa0, kb0, sc[jf]);
    sc[jf] = mfma_bf16(qa1, kb1, sc[jf]);
  }
  float mv[4];
#pragma unroll
  for (int jf = 0; jf < 4; ++jf)
    mv[jf] = (amask[b * 64 + jf * 16 + l15] == 0) ? -3.402823466e38f : 0.f;

  float rsum[4];
#pragma unroll
  for (int e = 0; e < 4; ++e) {
    const float s0 = sc[0][e] * 0.125f + mv[0];
    const float s1 = sc[1][e] * 0.125f + mv[1];
    const float s2 = sc[2][e] * 0.125f + mv[2];
    const float s3 = sc[3][e] * 0.125f + mv[3];
    float mx = fmaxf(fmaxf(s0, s1), fmaxf(s2, s3));
#pragma unroll
    for (int mk = 1; mk < 16; mk <<= 1) mx = fmaxf(mx, __shfl_xor(mx, mk, 64));
    const float p0 = __expf(s0 - mx), p1 = __expf(s1 - mx);
    const float p2 = __expf(s2 - mx), p3 = __expf(s3 - mx);
    float sm = p0 + p1 + p2 + p3;
#pragma unroll
    for (int mk = 1; mk < 16; mk <<= 1) sm += __shfl_xor(sm, mk, 64);
    rsum[e] = sm;
    const int prow = l4 * 4 + e;
    sP[wid][prow * 80 +  0 + l15] = f2bf(p0);
    sP[wid][prow * 80 + 16 + l15] = f2bf(p1);
    sP[wid][prow * 80 + 32 + l15] = f2bf(p2);
    sP[wid][prow * 80 + 48 + l15] = f2bf(p3);
  }
  __syncthreads();

  const short8 pa0 = *(const short8*)&sP[wid][l15 * 80 + l4 * 8];
  const short8 pa1 = *(const short8*)&sP[wid][l15 * 80 + 32 + l4 * 8];
#pragma unroll
  for (int jf = 0; jf < 4; ++jf) {
    f32x4 oc = (f32x4){0.f, 0.f, 0.f, 0.f};
    const short8 vb0 = *(const short8*)&sVT[(jf * 16 + l15) * 80 + l4 * 8];
    const short8 vb1 = *(const short8*)&sVT[(jf * 16 + l15) * 80 + 32 + l4 * 8];
    oc = mfma_bf16(pa0, vb0, oc);
    oc = mfma_bf16(pa1, vb1, oc);
#pragma unroll
    for (int e = 0; e < 4; ++e) {
      const int row = wid * 16 + l4 * 4 + e;
      o[obase + (size_t)row * 768 + jf * 16 + l15] = f2bf(oc[e] / rsum[e]);
    }
  }
}

// ---------------------------------------------------------------- launcher
extern "C" void kernel_launch(void* const* d_in, const int* in_sizes, int n_in,
                              void* d_out, int out_size, void* d_ws, size_t ws_size,
                              hipStream_t stream)
{
  (void)in_sizes; (void)n_in; (void)out_size; (void)ws_size;
  const int*   ids  = (const int*)  d_in[0];
  const int*   am   = (const int*)  d_in[1];
  const float* tok  = (const float*)d_in[2];
  const float* pos  = (const float*)d_in[3];
  const float* ln1g = (const float*)d_in[4];
  const float* ln1b = (const float*)d_in[5];
  const float* wq   = (const float*)d_in[6];
  const float* bq   = (const float*)d_in[7];
  const float* wk   = (const float*)d_in[8];
  const float* bk   = (const float*)d_in[9];
  const float* wv   = (const float*)d_in[10];
  const float* bv   = (const float*)d_in[11];
  const float* wo   = (const float*)d_in[12];
  const float* bo   = (const float*)d_in[13];
  const float* ln2g = (const float*)d_in[14];
  const float* ln2b = (const float*)d_in[15];
  const float* w1   = (const float*)d_in[16];
  const float* b1   = (const float*)d_in[17];
  const float* w2   = (const float*)d_in[18];
  const float* b2   = (const float*)d_in[19];
  const float* flng = (const float*)d_in[20];
  const float* flnb = (const float*)d_in[21];
  const float* hw   = (const float*)d_in[22];
  const float* hb   = (const float*)d_in[23];

  char* ws = (char*)d_ws;
  size_t off = 0;
  auto alloc = [&](size_t bytes) -> char* {
    char* p = ws + off; off += (bytes + 255) & ~(size_t)255; return p;
  };
  u16* wqkvT = (u16*)alloc((size_t)L_ * NQKV * D_ * 2);   // [L][2304][768]
  u16* woT = (u16*)alloc((size_t)L_ * D_ * D_ * 2);
  u16* w1T = (u16*)alloc((size_t)L_ * D_ * F_ * 2);
  u16* w2T = (u16*)alloc((size_t)L_ * D_ * F_ * 2);
  u16* hwT = (u16*)alloc((size_t)D_ * P_ * 2);
  float* bqkv = (float*)alloc((size_t)L_ * NQKV * 4);
  float* h = (float*)alloc((size_t)M_ * D_ * 4);
  u16* xb   = (u16*)alloc((size_t)M_ * D_ * 2);
  u16* qkvb = (u16*)alloc((size_t)M_ * NQKV * 2);
  u16* ob   = (u16*)alloc((size_t)M_ * D_ * 2);
  u16* m1   = (u16*)alloc((size_t)M_ * F_ * 2);

  const dim3 tb32(32, 8);
  const size_t LQKV = (size_t)NQKV * D_;
  wtrans_kernel<<<dim3(24, 24, 12), tb32, 0, stream>>>(wq, wqkvT,            768, 768, LQKV);
  wtrans_kernel<<<dim3(24, 24, 12), tb32, 0, stream>>>(wk, wqkvT + 589824,   768, 768, LQKV);
  wtrans_kernel<<<dim3(24, 24, 12), tb32, 0, stream>>>(wv, wqkvT + 1179648,  768, 768, LQKV);
  wtrans_kernel<<<dim3(24, 24, 12), tb32, 0, stream>>>(wo, woT, 768, 768, (size_t)D_ * D_);
  wtrans_kernel<<<dim3(96, 24, 12), tb32, 0, stream>>>(w1, w1T, 768, 3072, (size_t)D_ * F_);
  wtrans_kernel<<<dim3(24, 96, 12), tb32, 0, stream>>>(w2, w2T, 3072, 768, (size_t)D_ * F_);
  wtrans_kernel<<<dim3(24, 24, 1),  tb32, 0, stream>>>(hw, hwT, 768, 768, (size_t)D_ * P_);
  fusebias_kernel<<<108, 256, 0, stream>>>(bq, bk, bv, bqkv);

  embed_kernel<<<12288, 256, 0, stream>>>(ids, tok, pos, h);

  for (int l = 0; l < 12; ++l) {
    ln_kernel<false><<<4096, 256, 0, stream>>>(h, ln1g + l * 768, ln1b + l * 768, xb, nullptr);
    gemm256_kernel<0><<<dim3(9, 64), 512, 0, stream>>>(xb, 768, wqkvT + (size_t)l * LQKV,
                                                       bqkv + l * NQKV, nullptr, qkvb, M_, NQKV, 768);
    attn_kernel<<<3072, 256, 0, stream>>>(qkvb, am, ob);
    gemm256_kernel<1><<<dim3(3, 64), 512, 0, stream>>>(ob, 768, woT + (size_t)l * 589824,
                                                       bo + l * 768, h, h, M_, 768, 768);
    ln_kernel<false><<<4096, 256, 0, stream>>>(h, ln2g + l * 768, ln2b + l * 768, xb, nullptr);
    gemm256_kernel<2><<<dim3(12, 64), 512, 0, stream>>>(xb, 768, w1T + (size_t)l * 2359296,
                                                        b1 + l * 3072, nullptr, m1, M_, 3072, 768);
    gemm256_kernel<1><<<dim3(3, 64), 512, 0, stream>>>(m1, 3072, w2T + (size_t)l * 2359296,
                                                       b2 + l * 768, h, h, M_, 768, 3072);
  }

  ln_kernel<true><<<4096, 256, 0, stream>>>(h, flng, flnb, xb, (float*)d_out);
  gemm_kernel<3><<<dim3(6, 2), 256, 0, stream>>>(xb + 63 * 768, 64 * 768, hwT, hb, nullptr,
                                                 (float*)d_out + (size_t)M_ * D_, 256, 768, 768);
}